// Round 1
// baseline (340.791 us; speedup 1.0000x reference)
//
#include <hip/hip_runtime.h>
#include <hip/hip_bf16.h>
#include <math.h>

#define B_SZ 256
#define F_SZ 2048
#define C_SZ 16384
#define P_SZ 8
#define N_SZ 32

typedef __bf16 bf16x8 __attribute__((ext_vector_type(8)));
typedef float f32x4 __attribute__((ext_vector_type(4)));
typedef unsigned short us8 __attribute__((ext_vector_type(8)));

__device__ __forceinline__ unsigned short f2bf(float x) {
    union { float f; unsigned int u; } v; v.f = x;
    unsigned int r = v.u + 0x7FFFu + ((v.u >> 16) & 1u);  // RTN-even
    return (unsigned short)(r >> 16);
}

// ---------------- kernel 1: row norms + bf16 cast of inputs ----------------
__global__ __launch_bounds__(256) void prep_kernel(const float* __restrict__ inputs,
                                                   unsigned short* __restrict__ Abf,
                                                   float* __restrict__ norms) {
    const int row = blockIdx.x;
    const int tid = threadIdx.x;
    const float* rp = inputs + (size_t)row * F_SZ + tid * 8;
    float4 v0 = *(const float4*)(rp);
    float4 v1 = *(const float4*)(rp + 4);
    us8 o;
    o[0]=f2bf(v0.x); o[1]=f2bf(v0.y); o[2]=f2bf(v0.z); o[3]=f2bf(v0.w);
    o[4]=f2bf(v1.x); o[5]=f2bf(v1.y); o[6]=f2bf(v1.z); o[7]=f2bf(v1.w);
    *(us8*)(Abf + (size_t)row * F_SZ + tid * 8) = o;
    float ss = v0.x*v0.x + v0.y*v0.y + v0.z*v0.z + v0.w*v0.w
             + v1.x*v1.x + v1.y*v1.y + v1.z*v1.z + v1.w*v1.w;
    __shared__ float red[256];
    red[tid] = ss; __syncthreads();
    for (int s = 128; s > 0; s >>= 1) { if (tid < s) red[tid] += red[tid+s]; __syncthreads(); }
    if (tid == 0) norms[row] = sqrtf(red[0]);
}

// ---------------- kernel 2: outputs = inputs @ V^T (bf16 MFMA) ----------------
// BM=64, BN=128, BK=32; 256 threads = 4 waves in 2x2 grid; wave tile 32x64.
#define BM 64
#define BN 128
#define BK 32
#define LDK 40   // +8 bf16 pad -> row stride 80B (16B-aligned, 2-way-bank free)

__global__ __launch_bounds__(256) void gemm_kernel(const unsigned short* __restrict__ Abf,
                                                   const float* __restrict__ V,
                                                   float* __restrict__ Cout) {
    __shared__ unsigned short As[BM * LDK];
    __shared__ unsigned short Bs[BN * LDK];
    const int tid = threadIdx.x;
    const int lane = tid & 63;
    const int wid = tid >> 6;
    const int wm = wid >> 1, wn = wid & 1;
    const int q = lane >> 4, l16 = lane & 15;
    const int bm0 = blockIdx.y * BM;
    const int bn0 = blockIdx.x * BN;

    f32x4 acc[2][4];
    #pragma unroll
    for (int i = 0; i < 2; i++)
        #pragma unroll
        for (int j = 0; j < 4; j++) acc[i][j] = (f32x4){0.f, 0.f, 0.f, 0.f};

    // A staging: 64 rows x 32 bf16 = 4KB. 4 threads/row, 8 bf16 (16B) each.
    const int ar = tid >> 2, aseg = tid & 3;
    const unsigned short* Ag = Abf + (size_t)(bm0 + ar) * F_SZ + aseg * 8;
    unsigned short* Asd = &As[ar * LDK + aseg * 8];

    // B staging: 128 rows x 32 fp32 = 16KB. 2 threads/row, 16 fp32 each, cvt->bf16.
    const int br = tid >> 1, bseg = tid & 1;
    const float* Bg = V + (size_t)(bn0 + br) * F_SZ + bseg * 16;
    unsigned short* Bsd = &Bs[br * LDK + bseg * 16];

    for (int k0 = 0; k0 < F_SZ; k0 += BK) {
        us8 av = *(const us8*)(Ag + k0);
        float4 b0 = *(const float4*)(Bg + k0);
        float4 b1 = *(const float4*)(Bg + k0 + 4);
        float4 b2 = *(const float4*)(Bg + k0 + 8);
        float4 b3 = *(const float4*)(Bg + k0 + 12);
        __syncthreads();   // previous iter's frag reads done before overwrite
        *(us8*)Asd = av;
        us8 w0, w1;
        w0[0]=f2bf(b0.x); w0[1]=f2bf(b0.y); w0[2]=f2bf(b0.z); w0[3]=f2bf(b0.w);
        w0[4]=f2bf(b1.x); w0[5]=f2bf(b1.y); w0[6]=f2bf(b1.z); w0[7]=f2bf(b1.w);
        w1[0]=f2bf(b2.x); w1[1]=f2bf(b2.y); w1[2]=f2bf(b2.z); w1[3]=f2bf(b2.w);
        w1[4]=f2bf(b3.x); w1[5]=f2bf(b3.y); w1[6]=f2bf(b3.z); w1[7]=f2bf(b3.w);
        *(us8*)Bsd = w0;
        *(us8*)(Bsd + 8) = w1;
        __syncthreads();

        bf16x8 af[2], bfv[4];
        #pragma unroll
        for (int mi = 0; mi < 2; mi++)
            af[mi] = *(const bf16x8*)&As[(wm*32 + mi*16 + l16) * LDK + q*8];
        #pragma unroll
        for (int ni = 0; ni < 4; ni++)
            bfv[ni] = *(const bf16x8*)&Bs[(wn*64 + ni*16 + l16) * LDK + q*8];
        #pragma unroll
        for (int mi = 0; mi < 2; mi++)
            #pragma unroll
            for (int ni = 0; ni < 4; ni++)
                acc[mi][ni] = __builtin_amdgcn_mfma_f32_16x16x32_bf16(af[mi], bfv[ni], acc[mi][ni], 0, 0, 0);
    }

    // epilogue: D row=(lane>>4)*4+reg, col=lane&15  [verified m89/m91]
    #pragma unroll
    for (int mi = 0; mi < 2; mi++) {
        const int r0 = bm0 + wm*32 + mi*16 + q*4;
        #pragma unroll
        for (int ni = 0; ni < 4; ni++) {
            const int c0 = bn0 + wn*64 + ni*16 + l16;
            #pragma unroll
            for (int r = 0; r < 4; r++)
                Cout[(size_t)(r0 + r) * C_SZ + c0] = acc[mi][ni][r];
        }
    }
}

// ---------------- kernel 3: per-row softmax + pair matching + hard-pair sums ----------------
__global__ __launch_bounds__(256) void loss_rows_kernel(
    const float* __restrict__ inputs, const int* __restrict__ targets,
    const int* __restrict__ ppairs, const int* __restrict__ npairs,
    const int* __restrict__ indexs, const int* __restrict__ cluster,
    const float* __restrict__ outputs, const float* __restrict__ norms,
    float* __restrict__ bu_part, float* __restrict__ hp_part,
    float* __restrict__ hn_part, int* __restrict__ flag_part)
{
    const int i = blockIdx.x;
    const int tid = threadIdx.x;
    __shared__ int idxbuf[B_SZ];
    __shared__ int pj[P_SZ];
    __shared__ int nj[N_SZ];
    __shared__ float simp[P_SZ];
    __shared__ float simn[N_SZ];
    __shared__ float tnv[N_SZ];
    __shared__ float red[256];
    __shared__ float s_max, s_tp;

    idxbuf[tid] = indexs[tid];
    __syncthreads();

    const float* row = outputs + (size_t)i * C_SZ;
    const float ni_norm = norms[i];

    // log-softmax denominator: max then sum-exp
    float m = -INFINITY;
    for (int c = tid; c < C_SZ; c += 256) m = fmaxf(m, row[c]);
    red[tid] = m; __syncthreads();
    for (int s = 128; s > 0; s >>= 1) { if (tid < s) red[tid] = fmaxf(red[tid], red[tid+s]); __syncthreads(); }
    if (tid == 0) s_max = red[0];
    __syncthreads();
    const float mx = s_max;
    float se = 0.f;
    for (int c = tid; c < C_SZ; c += 256) se += expf(row[c] - mx);
    red[tid] = se; __syncthreads();
    for (int s = 128; s > 0; s >>= 1) { if (tid < s) red[tid] += red[tid+s]; __syncthreads(); }

    // pair matching (indexs is a permutation -> at most one match; argmax = first)
    if (tid < P_SZ) {
        int pp = ppairs[i * P_SZ + tid];
        int f = -1;
        if (pp >= 0) for (int j = 0; j < B_SZ; j++) if (idxbuf[j] == pp) { f = j; break; }
        pj[tid] = f;
    } else if (tid < P_SZ + N_SZ) {
        int t = tid - P_SZ;
        int np = npairs[i * N_SZ + t];
        int f = -1;
        if (np >= 0) for (int j = 0; j < B_SZ; j++) if (idxbuf[j] == np) { f = j; break; }
        nj[t] = f;
        int cid = cluster[np < 0 ? 0 : np];           // jnp.clip(npairs, 0)
        tnv[t] = row[cid] / ni_norm;                  // tsims[i, ncid] = outputs/norm
    }
    if (tid == P_SZ + N_SZ) s_tp = row[targets[i]] / ni_norm;
    __syncthreads();

    // in-batch sims (fp32, exact semantics incl. self-match ~1.0): one pair per wave round-robin
    const int lane = tid & 63, wv = tid >> 6;
    for (int qq = wv; qq < P_SZ + N_SZ; qq += 4) {
        int j = (qq < P_SZ) ? pj[qq] : nj[qq - P_SZ];
        float s = 0.f;
        if (j >= 0) {
            const float* xi = inputs + (size_t)i * F_SZ;
            const float* xj = inputs + (size_t)j * F_SZ;
            float d = 0.f;
            for (int k = lane; k < F_SZ; k += 64) d += xi[k] * xj[k];
            for (int off = 32; off > 0; off >>= 1) d += __shfl_down(d, off);
            s = d / (ni_norm * norms[j]);
        }
        if (lane == 0) { if (qq < P_SZ) simp[qq] = s; else simn[qq - P_SZ] = s; }
    }
    __syncthreads();

    if (tid == 0) {
        float logZ = mx + logf(red[0]);
        bu_part[i] = -(row[targets[i]] - logZ);

        float psims[P_SZ + 1]; bool pmask[P_SZ + 1];
        for (int p = 0; p < P_SZ; p++) {
            int pp = ppairs[i * P_SZ + p];
            pmask[p] = (pj[p] >= 0) && (pp >= 0);
            psims[p] = simp[p];
        }
        psims[P_SZ] = s_tp; pmask[P_SZ] = (s_tp != 0.0f);

        float nsims[2 * N_SZ]; bool nmask[2 * N_SZ];
        for (int t = 0; t < N_SZ; t++) {
            int np = npairs[i * N_SZ + t];
            nmask[t] = (nj[t] >= 0) && (np >= 0);
            nsims[t] = simn[t];
            nsims[N_SZ + t] = tnv[t];
            nmask[N_SZ + t] = (np >= 0) && (tnv[t] != 0.0f);
        }
        bool anyp = false, anyn = false;
        float maxn = -INFINITY, minp = INFINITY;
        for (int t = 0; t < 2 * N_SZ; t++) if (nmask[t]) { anyn = true; maxn = fmaxf(maxn, nsims[t]); }
        for (int p = 0; p < P_SZ + 1; p++) if (pmask[p]) { anyp = true; minp = fminf(minp, psims[p]); }
        float p_thrd = (anyn ? maxn : -3.0f) + 0.1f;
        float n_thrd = (anyp ? minp : 3.0f) - 0.1f;
        float hps = 0.f, hns = 0.f; int fl = 0;
        for (int p = 0; p < P_SZ + 1; p++)
            if (pmask[p] && psims[p] < p_thrd) { fl |= 1; hps += expf(-2.0f * (psims[p] - 0.5f)); }
        for (int t = 0; t < 2 * N_SZ; t++)
            if (nmask[t] && nsims[t] > n_thrd && nsims[t] < 0.999999f) { fl |= 2; hns += expf(50.0f * (nsims[t] - 0.5f)); }
        hp_part[i] = hps; hn_part[i] = hns; flag_part[i] = fl;
    }
}

// ---------------- kernel 4: final scalar reduce ----------------
__global__ __launch_bounds__(256) void finalize_kernel(
    const float* __restrict__ bu_part, const float* __restrict__ hp_part,
    const float* __restrict__ hn_part, const int* __restrict__ flag_part,
    float* __restrict__ d_out)
{
    __shared__ float r1[256], r2[256], r3[256];
    __shared__ int rf[256];
    const int tid = threadIdx.x;
    r1[tid] = bu_part[tid]; r2[tid] = hp_part[tid]; r3[tid] = hn_part[tid]; rf[tid] = flag_part[tid];
    __syncthreads();
    for (int s = 128; s > 0; s >>= 1) {
        if (tid < s) { r1[tid] += r1[tid+s]; r2[tid] += r2[tid+s]; r3[tid] += r3[tid+s]; rf[tid] |= rf[tid+s]; }
        __syncthreads();
    }
    if (tid == 0) {
        float bu = r1[0] / (float)B_SZ;
        float hp_loss = (rf[0] & 1) ? 0.5f * log1pf(r2[0]) : 0.0f;
        float hn_loss = (rf[0] & 2) ? (1.0f / 50.0f) * log1pf(r3[0]) : 0.0f;
        d_out[0] = 1.0f * bu + 10.0f * (hp_loss + hn_loss);   // W_BU=1, W_H=10
    }
}

extern "C" void kernel_launch(void* const* d_in, const int* in_sizes, int n_in,
                              void* d_out, int out_size, void* d_ws, size_t ws_size,
                              hipStream_t stream) {
    const float* inputs  = (const float*)d_in[0];
    const int*   targets = (const int*)d_in[1];
    const int*   ppairs  = (const int*)d_in[2];
    const int*   npairs  = (const int*)d_in[3];
    const int*   indexs  = (const int*)d_in[4];
    const int*   cluster = (const int*)d_in[5];
    const float* V       = (const float*)d_in[6];
    float* out = (float*)d_out;           // [0] = loss, [1..] = outputs row-major [B][C]

    char* ws = (char*)d_ws;
    unsigned short* Abf = (unsigned short*)ws;                       // 256*2048*2 = 1 MB
    float* norms   = (float*)(ws + (size_t)B_SZ * F_SZ * 2);
    float* bu_part = norms + B_SZ;
    float* hp_part = bu_part + B_SZ;
    float* hn_part = hp_part + B_SZ;
    int*   flag_part = (int*)(hn_part + B_SZ);

    prep_kernel<<<B_SZ, 256, 0, stream>>>(inputs, Abf, norms);
    gemm_kernel<<<dim3(C_SZ / BN, B_SZ / BM), 256, 0, stream>>>(Abf, V, out + 1);
    loss_rows_kernel<<<B_SZ, 256, 0, stream>>>(inputs, targets, ppairs, npairs, indexs,
                                               cluster, out + 1, norms,
                                               bu_part, hp_part, hn_part, flag_part);
    finalize_kernel<<<1, 256, 0, stream>>>(bu_part, hp_part, hn_part, flag_part, out);
}

// Round 2
// 316.931 us; speedup vs baseline: 1.0753x; 1.0753x over previous
//
#include <hip/hip_runtime.h>
#include <hip/hip_bf16.h>
#include <math.h>

#define B_SZ 256
#define F_SZ 2048
#define C_SZ 16384
#define P_SZ 8
#define N_SZ 32

typedef __bf16 bf16x8 __attribute__((ext_vector_type(8)));
typedef float f32x4 __attribute__((ext_vector_type(4)));
typedef unsigned short us8 __attribute__((ext_vector_type(8)));

typedef __attribute__((address_space(3))) unsigned int lds_u32;
typedef __attribute__((address_space(1))) const unsigned int glb_u32;

__device__ __forceinline__ unsigned short f2bf(float x) {
    union { float f; unsigned int u; } v; v.f = x;
    unsigned int r = v.u + 0x7FFFu + ((v.u >> 16) & 1u);  // RTN-even
    return (unsigned short)(r >> 16);
}

// ---------------- kernel 1: row norms + bf16 cast of inputs ----------------
__global__ __launch_bounds__(256) void prep_kernel(const float* __restrict__ inputs,
                                                   unsigned short* __restrict__ Abf,
                                                   float* __restrict__ norms) {
    const int row = blockIdx.x;
    const int tid = threadIdx.x;
    const float* rp = inputs + (size_t)row * F_SZ + tid * 8;
    float4 v0 = *(const float4*)(rp);
    float4 v1 = *(const float4*)(rp + 4);
    us8 o;
    o[0]=f2bf(v0.x); o[1]=f2bf(v0.y); o[2]=f2bf(v0.z); o[3]=f2bf(v0.w);
    o[4]=f2bf(v1.x); o[5]=f2bf(v1.y); o[6]=f2bf(v1.z); o[7]=f2bf(v1.w);
    *(us8*)(Abf + (size_t)row * F_SZ + tid * 8) = o;
    float ss = v0.x*v0.x + v0.y*v0.y + v0.z*v0.z + v0.w*v0.w
             + v1.x*v1.x + v1.y*v1.y + v1.z*v1.z + v1.w*v1.w;
    __shared__ float red[256];
    red[tid] = ss; __syncthreads();
    for (int s = 128; s > 0; s >>= 1) { if (tid < s) red[tid] += red[tid+s]; __syncthreads(); }
    if (tid == 0) norms[row] = sqrtf(red[0]);
}

// ---------------- kernel 2: outputs = inputs @ V^T (bf16 MFMA, dbuf) ----------------
// BM=128, BN=64, BK=64; 256 threads = 4 waves, wave tile 32x64 (mi 2 x ni 4).
// A: global_load_lds w=16, XOR chunk swizzle via lane->global mapping:
//    chunk (row, c) stored at slot row*8 + (c ^ (row&7)); slot s holds 16B.
// B: fp32 loads -> VGPR -> bf16 -> padded LDS (72 shorts/row, 2-way free).
#define BM 128
#define BN 64
#define BK 64
#define BPAD 72
#define KITERS (F_SZ / BK)

__global__ __launch_bounds__(256) void gemm_kernel(const unsigned short* __restrict__ Abf,
                                                   const float* __restrict__ V,
                                                   float* __restrict__ Cout) {
    __shared__ unsigned short As[2][BM * BK];     // 2 x 16 KB, swizzled chunks
    __shared__ unsigned short Bs[2][BN * BPAD];   // 2 x 9 KB, padded

    const int tid = threadIdx.x;
    const int lane = tid & 63;
    const int wid = tid >> 6;
    const int q = lane >> 4, l16 = lane & 15;
    const int bm0 = blockIdx.y * BM;
    const int bn0 = blockIdx.x * BN;

    f32x4 acc[2][4];
    #pragma unroll
    for (int i = 0; i < 2; i++)
        #pragma unroll
        for (int j = 0; j < 4; j++) acc[i][j] = (f32x4){0.f, 0.f, 0.f, 0.f};

    // ---- A staging (global_load_lds): 4 issues x 256 threads x 16B = 16 KB
    const int arow = tid >> 3;                       // 0..31 (+ j*32 per issue)
    const int cfetch = (tid & 7) ^ (arow & 7);       // XOR swizzle in fetch map
    const unsigned short* AgBase = Abf + (size_t)(bm0 + arow) * F_SZ + cfetch * 8;

    // ---- B staging: thread -> (row = tid>>2, seg = tid&3), 16 fp32 each
    const int brow = tid >> 2, bseg = tid & 3;
    const float* BgBase = V + (size_t)(bn0 + brow) * F_SZ + bseg * 16;
    unsigned short* Bsd0 = &Bs[0][brow * BPAD + bseg * 16];
    unsigned short* Bsd1 = &Bs[1][brow * BPAD + bseg * 16];

    float4 b0, b1, b2, b3;

    auto issueA = [&](int buf, int k0) {
        #pragma unroll
        for (int j = 0; j < 4; j++) {
            __builtin_amdgcn_global_load_lds(
                (glb_u32*)(AgBase + (size_t)j * 32 * F_SZ + k0),
                (lds_u32*)&As[buf][(size_t)(j * 256 + wid * 64) * 8],
                16, 0, 0);
        }
    };
    auto loadB = [&](int k0) {
        b0 = *(const float4*)(BgBase + k0);
        b1 = *(const float4*)(BgBase + k0 + 4);
        b2 = *(const float4*)(BgBase + k0 + 8);
        b3 = *(const float4*)(BgBase + k0 + 12);
    };
    auto writeB = [&](unsigned short* dst) {
        us8 w0, w1;
        w0[0]=f2bf(b0.x); w0[1]=f2bf(b0.y); w0[2]=f2bf(b0.z); w0[3]=f2bf(b0.w);
        w0[4]=f2bf(b1.x); w0[5]=f2bf(b1.y); w0[6]=f2bf(b1.z); w0[7]=f2bf(b1.w);
        w1[0]=f2bf(b2.x); w1[1]=f2bf(b2.y); w1[2]=f2bf(b2.z); w1[3]=f2bf(b2.w);
        w1[4]=f2bf(b3.x); w1[5]=f2bf(b3.y); w1[6]=f2bf(b3.z); w1[7]=f2bf(b3.w);
        *(us8*)dst = w0;
        *(us8*)(dst + 8) = w1;
    };

    // prologue: fill buffer 0
    issueA(0, 0);
    loadB(0);
    writeB(Bsd0);
    __syncthreads();   // compiler drains vmcnt (glds) + lgkmcnt before barrier

    for (int it = 0; it < KITERS; ++it) {
        const int cur = it & 1;
        const bool more = (it + 1) < KITERS;
        if (more) {
            issueA(cur ^ 1, (it + 1) * BK);
            loadB((it + 1) * BK);
        }
        // compute on buf cur
        #pragma unroll
        for (int ks = 0; ks < 2; ++ks) {
            bf16x8 af[2], bfv[4];
            #pragma unroll
            for (int mi = 0; mi < 2; ++mi) {
                const int row = wid * 32 + mi * 16 + l16;
                const int kc = ks * 4 + q;
                af[mi] = *(const bf16x8*)&As[cur][(size_t)(row * 8 + (kc ^ (row & 7))) * 8];
            }
            #pragma unroll
            for (int ni = 0; ni < 4; ++ni)
                bfv[ni] = *(const bf16x8*)&Bs[cur][(ni * 16 + l16) * BPAD + ks * 32 + q * 8];
            #pragma unroll
            for (int mi = 0; mi < 2; ++mi)
                #pragma unroll
                for (int ni = 0; ni < 4; ++ni)
                    acc[mi][ni] = __builtin_amdgcn_mfma_f32_16x16x32_bf16(af[mi], bfv[ni], acc[mi][ni], 0, 0, 0);
        }
        if (more) writeB(cur ? Bsd0 : Bsd1);
        __syncthreads();
    }

    // epilogue: D row=(lane>>4)*4+reg, col=lane&15  [verified m89/m91]
    #pragma unroll
    for (int mi = 0; mi < 2; ++mi) {
        const int r0 = bm0 + wid * 32 + mi * 16 + q * 4;
        #pragma unroll
        for (int ni = 0; ni < 4; ++ni) {
            const int c0 = bn0 + ni * 16 + l16;
            #pragma unroll
            for (int r = 0; r < 4; ++r)
                Cout[(size_t)(r0 + r) * C_SZ + c0] = acc[mi][ni][r];
        }
    }
}

// ---------------- kernel 3: per-row softmax + pair matching + hard-pair sums ----------------
__global__ __launch_bounds__(256) void loss_rows_kernel(
    const float* __restrict__ inputs, const int* __restrict__ targets,
    const int* __restrict__ ppairs, const int* __restrict__ npairs,
    const int* __restrict__ indexs, const int* __restrict__ cluster,
    const float* __restrict__ outputs, const float* __restrict__ norms,
    float* __restrict__ bu_part, float* __restrict__ hp_part,
    float* __restrict__ hn_part, int* __restrict__ flag_part)
{
    const int i = blockIdx.x;
    const int tid = threadIdx.x;
    __shared__ int idxbuf[B_SZ];
    __shared__ int pj[P_SZ];
    __shared__ int nj[N_SZ];
    __shared__ float simp[P_SZ];
    __shared__ float simn[N_SZ];
    __shared__ float tnv[N_SZ];
    __shared__ float red_m[256], red_s[256];
    __shared__ float s_tp;

    idxbuf[tid] = indexs[tid];
    __syncthreads();

    const float* row = outputs + (size_t)i * C_SZ;
    const float ni_norm = norms[i];

    // single-pass online softmax denominator
    float m = -INFINITY, se = 0.f;
    for (int c = tid; c < C_SZ; c += 256) {
        float v = row[c];
        float nm = fmaxf(m, v);
        se = se * __expf(m - nm) + __expf(v - nm);
        m = nm;
    }
    red_m[tid] = m; red_s[tid] = se; __syncthreads();
    for (int s = 128; s > 0; s >>= 1) {
        if (tid < s) {
            float m2 = red_m[tid + s], s2 = red_s[tid + s];
            float m1 = red_m[tid],      s1 = red_s[tid];
            float nm = fmaxf(m1, m2);
            red_s[tid] = s1 * __expf(m1 - nm) + s2 * __expf(m2 - nm);
            red_m[tid] = nm;
        }
        __syncthreads();
    }

    // pair matching (indexs is a permutation -> at most one match; argmax = first)
    if (tid < P_SZ) {
        int pp = ppairs[i * P_SZ + tid];
        int f = -1;
        if (pp >= 0) for (int j = 0; j < B_SZ; j++) if (idxbuf[j] == pp) { f = j; break; }
        pj[tid] = f;
    } else if (tid < P_SZ + N_SZ) {
        int t = tid - P_SZ;
        int np = npairs[i * N_SZ + t];
        int f = -1;
        if (np >= 0) for (int j = 0; j < B_SZ; j++) if (idxbuf[j] == np) { f = j; break; }
        nj[t] = f;
        int cid = cluster[np < 0 ? 0 : np];           // jnp.clip(npairs, 0)
        tnv[t] = row[cid] / ni_norm;                  // tsims[i, ncid] = outputs/norm
    }
    if (tid == P_SZ + N_SZ) s_tp = row[targets[i]] / ni_norm;
    __syncthreads();

    // in-batch sims (fp32, exact semantics incl. self-match ~1.0): one pair per wave round-robin
    const int lane = tid & 63, wv = tid >> 6;
    for (int qq = wv; qq < P_SZ + N_SZ; qq += 4) {
        int j = (qq < P_SZ) ? pj[qq] : nj[qq - P_SZ];
        float s = 0.f;
        if (j >= 0) {
            const float* xi = inputs + (size_t)i * F_SZ;
            const float* xj = inputs + (size_t)j * F_SZ;
            float d = 0.f;
            for (int k = lane; k < F_SZ; k += 64) d += xi[k] * xj[k];
            for (int off = 32; off > 0; off >>= 1) d += __shfl_down(d, off);
            s = d / (ni_norm * norms[j]);
        }
        if (lane == 0) { if (qq < P_SZ) simp[qq] = s; else simn[qq - P_SZ] = s; }
    }
    __syncthreads();

    if (tid == 0) {
        float logZ = red_m[0] + logf(red_s[0]);
        bu_part[i] = -(row[targets[i]] - logZ);

        float psims[P_SZ + 1]; bool pmask[P_SZ + 1];
        for (int p = 0; p < P_SZ; p++) {
            int pp = ppairs[i * P_SZ + p];
            pmask[p] = (pj[p] >= 0) && (pp >= 0);
            psims[p] = simp[p];
        }
        psims[P_SZ] = s_tp; pmask[P_SZ] = (s_tp != 0.0f);

        float nsims[2 * N_SZ]; bool nmask[2 * N_SZ];
        for (int t = 0; t < N_SZ; t++) {
            int np = npairs[i * N_SZ + t];
            nmask[t] = (nj[t] >= 0) && (np >= 0);
            nsims[t] = simn[t];
            nsims[N_SZ + t] = tnv[t];
            nmask[N_SZ + t] = (np >= 0) && (tnv[t] != 0.0f);
        }
        bool anyp = false, anyn = false;
        float maxn = -INFINITY, minp = INFINITY;
        for (int t = 0; t < 2 * N_SZ; t++) if (nmask[t]) { anyn = true; maxn = fmaxf(maxn, nsims[t]); }
        for (int p = 0; p < P_SZ + 1; p++) if (pmask[p]) { anyp = true; minp = fminf(minp, psims[p]); }
        float p_thrd = (anyn ? maxn : -3.0f) + 0.1f;
        float n_thrd = (anyp ? minp : 3.0f) - 0.1f;
        float hps = 0.f, hns = 0.f; int fl = 0;
        for (int p = 0; p < P_SZ + 1; p++)
            if (pmask[p] && psims[p] < p_thrd) { fl |= 1; hps += expf(-2.0f * (psims[p] - 0.5f)); }
        for (int t = 0; t < 2 * N_SZ; t++)
            if (nmask[t] && nsims[t] > n_thrd && nsims[t] < 0.999999f) { fl |= 2; hns += expf(50.0f * (nsims[t] - 0.5f)); }
        hp_part[i] = hps; hn_part[i] = hns; flag_part[i] = fl;
    }
}

// ---------------- kernel 4: final scalar reduce ----------------
__global__ __launch_bounds__(256) void finalize_kernel(
    const float* __restrict__ bu_part, const float* __restrict__ hp_part,
    const float* __restrict__ hn_part, const int* __restrict__ flag_part,
    float* __restrict__ d_out)
{
    __shared__ float r1[256], r2[256], r3[256];
    __shared__ int rf[256];
    const int tid = threadIdx.x;
    r1[tid] = bu_part[tid]; r2[tid] = hp_part[tid]; r3[tid] = hn_part[tid]; rf[tid] = flag_part[tid];
    __syncthreads();
    for (int s = 128; s > 0; s >>= 1) {
        if (tid < s) { r1[tid] += r1[tid+s]; r2[tid] += r2[tid+s]; r3[tid] += r3[tid+s]; rf[tid] |= rf[tid+s]; }
        __syncthreads();
    }
    if (tid == 0) {
        float bu = r1[0] / (float)B_SZ;
        float hp_loss = (rf[0] & 1) ? 0.5f * log1pf(r2[0]) : 0.0f;
        float hn_loss = (rf[0] & 2) ? (1.0f / 50.0f) * log1pf(r3[0]) : 0.0f;
        d_out[0] = 1.0f * bu + 10.0f * (hp_loss + hn_loss);   // W_BU=1, W_H=10
    }
}

extern "C" void kernel_launch(void* const* d_in, const int* in_sizes, int n_in,
                              void* d_out, int out_size, void* d_ws, size_t ws_size,
                              hipStream_t stream) {
    const float* inputs  = (const float*)d_in[0];
    const int*   targets = (const int*)d_in[1];
    const int*   ppairs  = (const int*)d_in[2];
    const int*   npairs  = (const int*)d_in[3];
    const int*   indexs  = (const int*)d_in[4];
    const int*   cluster = (const int*)d_in[5];
    const float* V       = (const float*)d_in[6];
    float* out = (float*)d_out;           // [0] = loss, [1..] = outputs row-major [B][C]

    char* ws = (char*)d_ws;
    unsigned short* Abf = (unsigned short*)ws;                       // 256*2048*2 = 1 MB
    float* norms   = (float*)(ws + (size_t)B_SZ * F_SZ * 2);
    float* bu_part = norms + B_SZ;
    float* hp_part = bu_part + B_SZ;
    float* hn_part = hp_part + B_SZ;
    int*   flag_part = (int*)(hn_part + B_SZ);

    prep_kernel<<<B_SZ, 256, 0, stream>>>(inputs, Abf, norms);
    gemm_kernel<<<dim3(C_SZ / BN, B_SZ / BM), 256, 0, stream>>>(Abf, V, out + 1);
    loss_rows_kernel<<<B_SZ, 256, 0, stream>>>(inputs, targets, ppairs, npairs, indexs,
                                               cluster, out + 1, norms,
                                               bu_part, hp_part, hn_part, flag_part);
    finalize_kernel<<<1, 256, 0, stream>>>(bu_part, hp_part, hn_part, flag_part, out);
}

// Round 3
// 302.804 us; speedup vs baseline: 1.1255x; 1.0467x over previous
//
#include <hip/hip_runtime.h>
#include <hip/hip_bf16.h>
#include <math.h>

#define B_SZ 256
#define F_SZ 2048
#define C_SZ 16384
#define P_SZ 8
#define N_SZ 32
#define NTILE 256   // C_SZ / BN column tiles per row

typedef __bf16 bf16x8 __attribute__((ext_vector_type(8)));
typedef float f32x4 __attribute__((ext_vector_type(4)));
typedef unsigned short us8 __attribute__((ext_vector_type(8)));

typedef __attribute__((address_space(3))) unsigned int lds_u32;
typedef __attribute__((address_space(1))) const unsigned int glb_u32;

__device__ __forceinline__ unsigned short f2bf(float x) {
    union { float f; unsigned int u; } v; v.f = x;
    unsigned int r = v.u + 0x7FFFu + ((v.u >> 16) & 1u);  // RTN-even
    return (unsigned short)(r >> 16);
}

// ---------------- kernel 1: row norms + bf16 cast of inputs ----------------
__global__ __launch_bounds__(256) void prep_kernel(const float* __restrict__ inputs,
                                                   unsigned short* __restrict__ Abf,
                                                   float* __restrict__ norms) {
    const int row = blockIdx.x;
    const int tid = threadIdx.x;
    const float* rp = inputs + (size_t)row * F_SZ + tid * 8;
    float4 v0 = *(const float4*)(rp);
    float4 v1 = *(const float4*)(rp + 4);
    us8 o;
    o[0]=f2bf(v0.x); o[1]=f2bf(v0.y); o[2]=f2bf(v0.z); o[3]=f2bf(v0.w);
    o[4]=f2bf(v1.x); o[5]=f2bf(v1.y); o[6]=f2bf(v1.z); o[7]=f2bf(v1.w);
    *(us8*)(Abf + (size_t)row * F_SZ + tid * 8) = o;
    float ss = v0.x*v0.x + v0.y*v0.y + v0.z*v0.z + v0.w*v0.w
             + v1.x*v1.x + v1.y*v1.y + v1.z*v1.z + v1.w*v1.w;
    __shared__ float red[256];
    red[tid] = ss; __syncthreads();
    for (int s = 128; s > 0; s >>= 1) { if (tid < s) red[tid] += red[tid+s]; __syncthreads(); }
    if (tid == 0) norms[row] = sqrtf(red[0]);
}

// ---------------- kernel 2: outputs = inputs @ V^T (bf16 MFMA, dbuf) ----------------
// BM=128, BN=64, BK=64; 256 threads = 4 waves, wave tile 32x64 (mi 2 x ni 4).
// Fused epilogue: per-row partial softmax (max, sumexp) over this block's 64 cols.
#define BM 128
#define BN 64
#define BK 64
#define BPAD 72
#define KITERS (F_SZ / BK)

__global__ __launch_bounds__(256) void gemm_kernel(const unsigned short* __restrict__ Abf,
                                                   const float* __restrict__ V,
                                                   float* __restrict__ Cout,
                                                   float* __restrict__ pmax,
                                                   float* __restrict__ psum) {
    __shared__ unsigned short As[2][BM * BK];     // 2 x 16 KB, swizzled chunks
    __shared__ unsigned short Bs[2][BN * BPAD];   // 2 x 9 KB, padded

    const int tid = threadIdx.x;
    const int lane = tid & 63;
    const int wid = tid >> 6;
    const int q = lane >> 4, l16 = lane & 15;
    const int bm0 = blockIdx.y * BM;
    const int bn0 = blockIdx.x * BN;

    f32x4 acc[2][4];
    #pragma unroll
    for (int i = 0; i < 2; i++)
        #pragma unroll
        for (int j = 0; j < 4; j++) acc[i][j] = (f32x4){0.f, 0.f, 0.f, 0.f};

    // ---- A staging (global_load_lds): 4 issues x 256 threads x 16B = 16 KB
    const int arow = tid >> 3;                       // 0..31 (+ j*32 per issue)
    const int cfetch = (tid & 7) ^ (arow & 7);       // XOR swizzle in fetch map
    const unsigned short* AgBase = Abf + (size_t)(bm0 + arow) * F_SZ + cfetch * 8;

    // ---- B staging: thread -> (row = tid>>2, seg = tid&3), 16 fp32 each
    const int brow = tid >> 2, bseg = tid & 3;
    const float* BgBase = V + (size_t)(bn0 + brow) * F_SZ + bseg * 16;
    unsigned short* Bsd0 = &Bs[0][brow * BPAD + bseg * 16];
    unsigned short* Bsd1 = &Bs[1][brow * BPAD + bseg * 16];

    float4 b0, b1, b2, b3;

    auto issueA = [&](int buf, int k0) {
        #pragma unroll
        for (int j = 0; j < 4; j++) {
            __builtin_amdgcn_global_load_lds(
                (glb_u32*)(AgBase + (size_t)j * 32 * F_SZ + k0),
                (lds_u32*)&As[buf][(size_t)(j * 256 + wid * 64) * 8],
                16, 0, 0);
        }
    };
    auto loadB = [&](int k0) {
        b0 = *(const float4*)(BgBase + k0);
        b1 = *(const float4*)(BgBase + k0 + 4);
        b2 = *(const float4*)(BgBase + k0 + 8);
        b3 = *(const float4*)(BgBase + k0 + 12);
    };
    auto writeB = [&](unsigned short* dst) {
        us8 w0, w1;
        w0[0]=f2bf(b0.x); w0[1]=f2bf(b0.y); w0[2]=f2bf(b0.z); w0[3]=f2bf(b0.w);
        w0[4]=f2bf(b1.x); w0[5]=f2bf(b1.y); w0[6]=f2bf(b1.z); w0[7]=f2bf(b1.w);
        w1[0]=f2bf(b2.x); w1[1]=f2bf(b2.y); w1[2]=f2bf(b2.z); w1[3]=f2bf(b2.w);
        w1[4]=f2bf(b3.x); w1[5]=f2bf(b3.y); w1[6]=f2bf(b3.z); w1[7]=f2bf(b3.w);
        *(us8*)dst = w0;
        *(us8*)(dst + 8) = w1;
    };

    // prologue: fill buffer 0
    issueA(0, 0);
    loadB(0);
    writeB(Bsd0);
    __syncthreads();

    for (int it = 0; it < KITERS; ++it) {
        const int cur = it & 1;
        const bool more = (it + 1) < KITERS;
        if (more) {
            issueA(cur ^ 1, (it + 1) * BK);
            loadB((it + 1) * BK);
        }
        #pragma unroll
        for (int ks = 0; ks < 2; ++ks) {
            bf16x8 af[2], bfv[4];
            #pragma unroll
            for (int mi = 0; mi < 2; ++mi) {
                const int row = wid * 32 + mi * 16 + l16;
                const int kc = ks * 4 + q;
                af[mi] = *(const bf16x8*)&As[cur][(size_t)(row * 8 + (kc ^ (row & 7))) * 8];
            }
            #pragma unroll
            for (int ni = 0; ni < 4; ++ni)
                bfv[ni] = *(const bf16x8*)&Bs[cur][(ni * 16 + l16) * BPAD + ks * 32 + q * 8];
            #pragma unroll
            for (int mi = 0; mi < 2; ++mi)
                #pragma unroll
                for (int ni = 0; ni < 4; ++ni)
                    acc[mi][ni] = __builtin_amdgcn_mfma_f32_16x16x32_bf16(af[mi], bfv[ni], acc[mi][ni], 0, 0, 0);
        }
        if (more) writeB(cur ? Bsd0 : Bsd1);
        __syncthreads();
    }

    // epilogue: D row=(lane>>4)*4+reg, col=lane&15  [verified m89/m91]
    #pragma unroll
    for (int mi = 0; mi < 2; ++mi) {
        const int r0 = bm0 + wid * 32 + mi * 16 + q * 4;
        #pragma unroll
        for (int ni = 0; ni < 4; ++ni) {
            const int c0 = bn0 + ni * 16 + l16;
            #pragma unroll
            for (int r = 0; r < 4; ++r)
                Cout[(size_t)(r0 + r) * C_SZ + c0] = acc[mi][ni][r];
        }
    }

    // fused partial softmax: per row, (max, sumexp) over this block's 64 columns.
    // Row r's 64 values live in 16 lanes (same q) x 4 ni frags -> in-reg max over ni,
    // then 16-lane xor-shuffle reduce (bits 0..3 stay within the l16 group).
    const int tileIdx = blockIdx.x;
    #pragma unroll
    for (int mi = 0; mi < 2; ++mi) {
        #pragma unroll
        for (int r = 0; r < 4; ++r) {
            float mloc = fmaxf(fmaxf(acc[mi][0][r], acc[mi][1][r]),
                               fmaxf(acc[mi][2][r], acc[mi][3][r]));
            #pragma unroll
            for (int off = 1; off < 16; off <<= 1)
                mloc = fmaxf(mloc, __shfl_xor(mloc, off, 64));
            float sloc = __expf(acc[mi][0][r] - mloc) + __expf(acc[mi][1][r] - mloc)
                       + __expf(acc[mi][2][r] - mloc) + __expf(acc[mi][3][r] - mloc);
            #pragma unroll
            for (int off = 1; off < 16; off <<= 1)
                sloc += __shfl_xor(sloc, off, 64);
            if (l16 == 0) {
                const int grow = bm0 + wid * 32 + mi * 16 + q * 4 + r;
                pmax[grow * NTILE + tileIdx] = mloc;
                psum[grow * NTILE + tileIdx] = sloc;
            }
        }
    }
}

// ---------------- kernel 3: merge softmax partials -> bu_part ----------------
__global__ __launch_bounds__(256) void softmax_combine_kernel(
    const float* __restrict__ pmax, const float* __restrict__ psum,
    const float* __restrict__ outputs, const int* __restrict__ targets,
    float* __restrict__ bu_part)
{
    const int row = blockIdx.x;
    const int tid = threadIdx.x;
    __shared__ float rm[256], rs[256];
    rm[tid] = pmax[row * NTILE + tid];
    rs[tid] = psum[row * NTILE + tid];
    __syncthreads();
    for (int s = 128; s > 0; s >>= 1) {
        if (tid < s) {
            float m1 = rm[tid], s1 = rs[tid];
            float m2 = rm[tid + s], s2 = rs[tid + s];
            float nm = fmaxf(m1, m2);
            rs[tid] = s1 * __expf(m1 - nm) + s2 * __expf(m2 - nm);
            rm[tid] = nm;
        }
        __syncthreads();
    }
    if (tid == 0) {
        float logZ = rm[0] + logf(rs[0]);
        bu_part[row] = -(outputs[(size_t)row * C_SZ + targets[row]] - logZ);
    }
}

// ---------------- kernel 4: pair matching + sims + hard-pair sums ----------------
__global__ __launch_bounds__(256) void pairs_kernel(
    const float* __restrict__ inputs, const int* __restrict__ targets,
    const int* __restrict__ ppairs, const int* __restrict__ npairs,
    const int* __restrict__ indexs, const int* __restrict__ cluster,
    const float* __restrict__ outputs, const float* __restrict__ norms,
    float* __restrict__ hp_part, float* __restrict__ hn_part,
    int* __restrict__ flag_part)
{
    const int i = blockIdx.x;
    const int tid = threadIdx.x;
    __shared__ int idxbuf[B_SZ];
    __shared__ int pj[P_SZ];
    __shared__ int nj[N_SZ];
    __shared__ float simp[P_SZ];
    __shared__ float simn[N_SZ];
    __shared__ float tnv[N_SZ];
    __shared__ float s_tp;

    idxbuf[tid] = indexs[tid];
    __syncthreads();

    const float* row = outputs + (size_t)i * C_SZ;
    const float ni_norm = norms[i];

    // pair matching (indexs is a permutation -> at most one match; argmax = first)
    if (tid < P_SZ) {
        int pp = ppairs[i * P_SZ + tid];
        int f = -1;
        if (pp >= 0) for (int j = 0; j < B_SZ; j++) if (idxbuf[j] == pp) { f = j; break; }
        pj[tid] = f;
    } else if (tid < P_SZ + N_SZ) {
        int t = tid - P_SZ;
        int np = npairs[i * N_SZ + t];
        int f = -1;
        if (np >= 0) for (int j = 0; j < B_SZ; j++) if (idxbuf[j] == np) { f = j; break; }
        nj[t] = f;
        int cid = cluster[np < 0 ? 0 : np];           // jnp.clip(npairs, 0)
        tnv[t] = row[cid] / ni_norm;                  // tsims[i, ncid] = outputs/norm
    }
    if (tid == P_SZ + N_SZ) s_tp = row[targets[i]] / ni_norm;
    __syncthreads();

    // in-batch sims (fp32, exact semantics incl. self-match ~1.0): one pair per wave round-robin
    const int lane = tid & 63, wv = tid >> 6;
    for (int qq = wv; qq < P_SZ + N_SZ; qq += 4) {
        int j = (qq < P_SZ) ? pj[qq] : nj[qq - P_SZ];
        float s = 0.f;
        if (j >= 0) {
            const float* xi = inputs + (size_t)i * F_SZ;
            const float* xj = inputs + (size_t)j * F_SZ;
            float d = 0.f;
            for (int k = lane; k < F_SZ; k += 64) d += xi[k] * xj[k];
            for (int off = 32; off > 0; off >>= 1) d += __shfl_down(d, off);
            s = d / (ni_norm * norms[j]);
        }
        if (lane == 0) { if (qq < P_SZ) simp[qq] = s; else simn[qq - P_SZ] = s; }
    }
    __syncthreads();

    if (tid == 0) {
        float psims[P_SZ + 1]; bool pmask[P_SZ + 1];
        for (int p = 0; p < P_SZ; p++) {
            int pp = ppairs[i * P_SZ + p];
            pmask[p] = (pj[p] >= 0) && (pp >= 0);
            psims[p] = simp[p];
        }
        psims[P_SZ] = s_tp; pmask[P_SZ] = (s_tp != 0.0f);

        float nsims[2 * N_SZ]; bool nmask[2 * N_SZ];
        for (int t = 0; t < N_SZ; t++) {
            int np = npairs[i * N_SZ + t];
            nmask[t] = (nj[t] >= 0) && (np >= 0);
            nsims[t] = simn[t];
            nsims[N_SZ + t] = tnv[t];
            nmask[N_SZ + t] = (np >= 0) && (tnv[t] != 0.0f);
        }
        bool anyp = false, anyn = false;
        float maxn = -INFINITY, minp = INFINITY;
        for (int t = 0; t < 2 * N_SZ; t++) if (nmask[t]) { anyn = true; maxn = fmaxf(maxn, nsims[t]); }
        for (int p = 0; p < P_SZ + 1; p++) if (pmask[p]) { anyp = true; minp = fminf(minp, psims[p]); }
        float p_thrd = (anyn ? maxn : -3.0f) + 0.1f;
        float n_thrd = (anyp ? minp : 3.0f) - 0.1f;
        float hps = 0.f, hns = 0.f; int fl = 0;
        for (int p = 0; p < P_SZ + 1; p++)
            if (pmask[p] && psims[p] < p_thrd) { fl |= 1; hps += expf(-2.0f * (psims[p] - 0.5f)); }
        for (int t = 0; t < 2 * N_SZ; t++)
            if (nmask[t] && nsims[t] > n_thrd && nsims[t] < 0.999999f) { fl |= 2; hns += expf(50.0f * (nsims[t] - 0.5f)); }
        hp_part[i] = hps; hn_part[i] = hns; flag_part[i] = fl;
    }
}

// ---------------- kernel 5: final scalar reduce ----------------
__global__ __launch_bounds__(256) void finalize_kernel(
    const float* __restrict__ bu_part, const float* __restrict__ hp_part,
    const float* __restrict__ hn_part, const int* __restrict__ flag_part,
    float* __restrict__ d_out)
{
    __shared__ float r1[256], r2[256], r3[256];
    __shared__ int rf[256];
    const int tid = threadIdx.x;
    r1[tid] = bu_part[tid]; r2[tid] = hp_part[tid]; r3[tid] = hn_part[tid]; rf[tid] = flag_part[tid];
    __syncthreads();
    for (int s = 128; s > 0; s >>= 1) {
        if (tid < s) { r1[tid] += r1[tid+s]; r2[tid] += r2[tid+s]; r3[tid] += r3[tid+s]; rf[tid] |= rf[tid+s]; }
        __syncthreads();
    }
    if (tid == 0) {
        float bu = r1[0] / (float)B_SZ;
        float hp_loss = (rf[0] & 1) ? 0.5f * log1pf(r2[0]) : 0.0f;
        float hn_loss = (rf[0] & 2) ? (1.0f / 50.0f) * log1pf(r3[0]) : 0.0f;
        d_out[0] = 1.0f * bu + 10.0f * (hp_loss + hn_loss);   // W_BU=1, W_H=10
    }
}

extern "C" void kernel_launch(void* const* d_in, const int* in_sizes, int n_in,
                              void* d_out, int out_size, void* d_ws, size_t ws_size,
                              hipStream_t stream) {
    const float* inputs  = (const float*)d_in[0];
    const int*   targets = (const int*)d_in[1];
    const int*   ppairs  = (const int*)d_in[2];
    const int*   npairs  = (const int*)d_in[3];
    const int*   indexs  = (const int*)d_in[4];
    const int*   cluster = (const int*)d_in[5];
    const float* V       = (const float*)d_in[6];
    float* out = (float*)d_out;           // [0] = loss, [1..] = outputs row-major [B][C]

    char* ws = (char*)d_ws;
    unsigned short* Abf = (unsigned short*)ws;                       // 1 MB
    float* norms   = (float*)(ws + (size_t)B_SZ * F_SZ * 2);
    float* bu_part = norms + B_SZ;
    float* hp_part = bu_part + B_SZ;
    float* hn_part = hp_part + B_SZ;
    int*   flag_part = (int*)(hn_part + B_SZ);
    float* pmax = (float*)(flag_part + B_SZ);                        // 256 KB
    float* psum = pmax + (size_t)B_SZ * NTILE;                       // 256 KB

    prep_kernel<<<B_SZ, 256, 0, stream>>>(inputs, Abf, norms);
    gemm_kernel<<<dim3(C_SZ / BN, B_SZ / BM), 256, 0, stream>>>(Abf, V, out + 1, pmax, psum);
    softmax_combine_kernel<<<B_SZ, 256, 0, stream>>>(pmax, psum, out + 1, targets, bu_part);
    pairs_kernel<<<B_SZ, 256, 0, stream>>>(inputs, targets, ppairs, npairs, indexs,
                                           cluster, out + 1, norms,
                                           hp_part, hn_part, flag_part);
    finalize_kernel<<<1, 256, 0, stream>>>(bu_part, hp_part, hn_part, flag_part, out);
}